// Round 12
// baseline (190.966 us; speedup 1.0000x reference)
//
#include <hip/hip_runtime.h>
#include <hip/hip_fp16.h>
#include <math.h>

// Problem dims
#define B_ 8
#define H_ 640
#define W_ 368
#define HW_ (H_*W_)
#define NP_ (B_*H_*W_)   // 1,884,160

#define FROWS 4          // h-rows per block in fused kbranch+fftW kernel
#define HP 645           // LDS pitch (float2) for ffthb kernel
#define TS 16            // spatial tile for fused tail kernel

typedef __attribute__((ext_vector_type(8))) short v8s;   // 8 bf16 (4 VGPR)
typedef __attribute__((ext_vector_type(4))) float v4f;   // MFMA acc

__device__ __forceinline__ float leaky_(float x){ return fmaxf(x, 0.01f*x); }

// fp32 -> bf16 round-to-nearest-even
__device__ __forceinline__ unsigned short f2bf(float x){
    unsigned u = __float_as_uint(x);
    u += 0x7FFFu + ((u >> 16) & 1u);
    return (unsigned short)(u >> 16);
}

__device__ __forceinline__ float2 cadd_(float2 a, float2 b){ return make_float2(a.x+b.x, a.y+b.y); }
__device__ __forceinline__ float2 csub_(float2 a, float2 b){ return make_float2(a.x-b.x, a.y-b.y); }
__device__ __forceinline__ float2 cmul_(float2 a, float c, float s){
    return make_float2(a.x*c - a.y*s, a.x*s + a.y*c);
}
__device__ __forceinline__ float2 cmulv_(float2 a, float2 w){
    return make_float2(a.x*w.x - a.y*w.y, a.x*w.y + a.y*w.x);
}

// DFT4 with +i convention
__device__ __forceinline__ void dft4p_(float2 p0, float2 p1, float2 p2, float2 p3,
                                       float2& z0, float2& z1, float2& z2, float2& z3){
    float2 s0 = cadd_(p0,p2), d0 = csub_(p0,p2);
    float2 s1 = cadd_(p1,p3), d1 = csub_(p1,p3);
    z0 = cadd_(s0,s1);
    z2 = csub_(s0,s1);
    z1 = make_float2(d0.x - d1.y, d0.y + d1.x);
    z3 = make_float2(d0.x + d1.y, d0.y - d1.x);
}

// 16-point DFT, +i convention
__device__ __forceinline__ void fft16p_(const float2* x, float2* X){
    const float C1 = 0.9238795325112867f, S1 = 0.3826834323650898f;
    const float R  = 0.7071067811865476f;
    float2 Y[4][4];
    #pragma unroll
    for (int b = 0; b < 4; ++b)
        dft4p_(x[b], x[4+b], x[8+b], x[12+b], Y[b][0], Y[b][1], Y[b][2], Y[b][3]);
    Y[1][1] = cmul_(Y[1][1],  C1,  S1);
    Y[1][2] = cmul_(Y[1][2],   R,   R);
    Y[1][3] = cmul_(Y[1][3],  S1,  C1);
    Y[2][1] = cmul_(Y[2][1],   R,   R);
    Y[2][2] = make_float2(-Y[2][2].y, Y[2][2].x);
    Y[2][3] = cmul_(Y[2][3],  -R,   R);
    Y[3][1] = cmul_(Y[3][1],  S1,  C1);
    Y[3][2] = cmul_(Y[3][2],  -R,   R);
    Y[3][3] = cmul_(Y[3][3], -C1, -S1);
    #pragma unroll
    for (int c = 0; c < 4; ++c)
        dft4p_(Y[0][c], Y[1][c], Y[2][c], Y[3][c], X[c], X[c+4], X[c+8], X[c+12]);
}

// 8-point DFT, +i convention
__device__ __forceinline__ void fft8p_(const float2* x, float2* X){
    const float R = 0.7071067811865476f;
    float2 Y0[4], Y1[4];
    dft4p_(x[0], x[2], x[4], x[6], Y0[0], Y0[1], Y0[2], Y0[3]);
    dft4p_(x[1], x[3], x[5], x[7], Y1[0], Y1[1], Y1[2], Y1[3]);
    float2 T0 = Y1[0];
    float2 T1 = cmul_(Y1[1],  R, R);
    float2 T2 = make_float2(-Y1[2].y, Y1[2].x);
    float2 T3 = cmul_(Y1[3], -R, R);
    X[0] = cadd_(Y0[0], T0);  X[4] = csub_(Y0[0], T0);
    X[1] = cadd_(Y0[1], T1);  X[5] = csub_(Y0[1], T1);
    X[2] = cadd_(Y0[2], T2);  X[6] = csub_(Y0[2], T2);
    X[3] = cadd_(Y0[3], T3);  X[7] = csub_(Y0[3], T3);
}

// ---------------------------------------------------------------------------
// Tables (float2 indices in T):
//   TW368P @    0 (368)  [n2*16+k1] = e^{+2pi i k1 n2/368}
//   TW640P @  368 (640)  [n2*16+k1] = e^{+2pi i k1 n2/640}
//   TW40P  @ 1008 ( 40)  [m2*8+j1]  = e^{+2pi i j1 m2/40}
//   F23P   @ 1048 (253)  [k2*11+m-1]= (cos,sin)(2pi k2 m/23)
// ---------------------------------------------------------------------------
__global__ void init_tables_kernel(float2* __restrict__ T){
    int i = blockIdx.x*blockDim.x + threadIdx.x;
    if (i >= 1301) return;
    int r, c, modN; int j;
    if      (i <  368){ j = i;        r = j%16; c = j/16; modN = 368; }
    else if (i < 1008){ j = i-368;    r = j%16; c = j/16; modN = 640; }
    else if (i < 1048){ j = i-1008;   r = j%8;  c = j/8;  modN = 40;  }
    else              { j = i-1048;   r = j/11; c = j%11 + 1; modN = 23; }
    int t = (int)(((long long)r * c) % modN);
    if (t > modN/2) t -= modN;
    float ang = (float)(6.283185307179586 * ((double)t / (double)modN));
    float s, co;
    sincosf(ang, &s, &co);
    T[i] = make_float2(co, s);
}

// ---------------------------------------------------------------------------
// K1 (fused kbranch + W-FFT), 512 threads: block = 4 h rows; 2 waves per row
// (halves of the 23-group range) -> serial MFMA chain 23 -> 12 groups.
// ---------------------------------------------------------------------------
__global__ __launch_bounds__(512) void kfftw_kernel(const float* __restrict__ ksp,
                               const float* __restrict__ wk,
                               const float* __restrict__ bk,
                               const float* __restrict__ w1,
                               const float* __restrict__ b1,
                               const float2* __restrict__ TW368P,
                               const float2* __restrict__ F23P,
                               float2* __restrict__ Bt){
    __shared__ unsigned short Sb[4836];     // 6 rows x 2ch x 372 + zero region
    __shared__ unsigned short Wr[8*512];    // per-wave 16px x 32oc transpose buf
    __shared__ float2 X[FROWS*369];         // fft working set (11,808 B)
    int t = threadIdx.x;
    int blk = blockIdx.x;                   // b*160 + h0/4
    int b  = blk / 160;
    int h0 = (blk - b*160) * FROWS;

    // Phase 1: stage rows h0-1 .. h0+4, both channels, halo col +1
    for (int seg = 0; seg < 12; ++seg){
        int r = seg >> 1, ic = seg & 1;
        int hh = h0 - 1 + r;
        int ok = ((unsigned)hh < 640u);
        const float* base = ksp + ((size_t)(b*2 + ic)*640 + (ok ? hh : 0))*368;
        for (int col = t; col < 372; col += 512){
            int c = col - 1;
            float v = (ok && (unsigned)c < 368u) ? base[c] : 0.f;
            Sb[seg*372 + col] = f2bf(v);
        }
    }
    for (int i = t; i < 372; i += 512) Sb[4464 + i] = 0;   // zero pad for k>=18

    int lane = t & 63, wave = t >> 6;
    int oc = lane & 15, q = lane >> 4;
    int l = wave >> 1, half = wave & 1;     // 2 waves per row

    int off[8];
    v8s bf0, bf1, b2f;
    #pragma unroll
    for (int j = 0; j < 8; ++j){
        int kk = q*8 + j;
        if (kk < 18){
            int ic = (kk >= 9) ? 1 : 0;
            int tt = kk - ic*9;
            int ty = tt/3, tx = tt - ty*3;
            off[j] = ((ty + l)*2 + ic)*372 + tx;
            bf0[j] = (short)f2bf(wk[oc*18 + kk]);
            bf1[j] = (short)f2bf(wk[(oc+16)*18 + kk]);
        } else {
            off[j] = 4464;                  // zeroed region
            bf0[j] = 0; bf1[j] = 0;
        }
        b2f[j] = (oc < 2) ? (short)f2bf(w1[oc*32 + kk]) : (short)0;
    }
    float bk0 = bk[oc], bk1 = bk[oc+16];
    float biasn = (oc == 1) ? b1[1] : b1[0];
    unsigned short* Wrw = Wr + (wave << 9);
    __syncthreads();

    // Phase 2: groups split across the row's 2 waves
    int gbeg = half ? 12 : 0;
    int gend = half ? 23 : 12;
    for (int g = gbeg; g < gend; ++g){
        int w0m = g*16 + oc;
        v8s af;
        #pragma unroll
        for (int j = 0; j < 8; ++j) af[j] = (short)Sb[off[j] + w0m];
        v4f d0 = {0.f,0.f,0.f,0.f}, d1 = {0.f,0.f,0.f,0.f};
        d0 = __builtin_amdgcn_mfma_f32_16x16x32_bf16(af, bf0, d0, 0, 0, 0);
        d1 = __builtin_amdgcn_mfma_f32_16x16x32_bf16(af, bf1, d1, 0, 0, 0);
        #pragma unroll
        for (int r = 0; r < 4; ++r){
            int px = q*4 + r;
            Wrw[px*32 + oc]      = f2bf(leaky_(d0[r] + bk0));
            Wrw[px*32 + 16 + oc] = f2bf(leaky_(d1[r] + bk1));
        }
        asm volatile("s_waitcnt lgkmcnt(0)" ::: "memory");
        const v8s* ap = (const v8s*)(Wrw + oc*32);
        v8s a2 = ap[q];
        v4f d2 = {0.f,0.f,0.f,0.f};
        d2 = __builtin_amdgcn_mfma_f32_16x16x32_bf16(a2, b2f, d2, 0, 0, 0);
        float vals[4], ov[4];
        #pragma unroll
        for (int r = 0; r < 4; ++r){
            vals[r] = leaky_(biasn + d2[r]);
            ov[r] = __shfl_xor(vals[r], 1);          // o1 (col 1) -> col-0 lane
        }
        if (oc == 0){
            int px = g*16 + q*4;                     // even -> signs +,-,+,-
            X[l*369 + px  ] = make_float2( vals[0],  ov[0]);
            X[l*369 + px+1] = make_float2(-vals[1], -ov[1]);
            X[l*369 + px+2] = make_float2( vals[2],  ov[2]);
            X[l*369 + px+3] = make_float2(-vals[3], -ov[3]);
        }
        asm volatile("s_waitcnt lgkmcnt(0)" ::: "memory");  // Wr reuse fence
    }
    __syncthreads();

    // Phase 3a: FFT16 over n1, items (l,n2) = 92
    if (t < 92){
        int ll = t & 3, n2 = t >> 2;
        float2 xr[16], Xo[16];
        #pragma unroll
        for (int n1 = 0; n1 < 16; ++n1) xr[n1] = X[ll*369 + 23*n1 + n2];
        fft16p_(xr, Xo);
        const float2* row = TW368P + n2*16;
        #pragma unroll
        for (int k1 = 0; k1 < 16; ++k1)
            X[ll*369 + 23*k1 + n2] = cmulv_(Xo[k1], row[k1]);
    }
    __syncthreads();

    // Phase 3b: DFT23 via pairs; 512 units = (k1, ll, eighth)
    {
        int k1 = t & 15, ll = (t >> 4) & 3, eighth = t >> 6;   // eighth wave-uniform
        const float2* xp = X + ll*369 + 23*k1;
        float2 x0 = xp[0];
        float2 u[11], d[11];
        #pragma unroll
        for (int m = 1; m <= 11; ++m){
            float2 a = xp[m], bb = xp[23-m];
            u[m-1] = cadd_(a, bb);
            d[m-1] = csub_(a, bb);
        }
        __syncthreads();
        int k2beg = eighth*3;
        int k2end = min(k2beg + 3, 23);
        for (int k2 = k2beg; k2 < k2end; ++k2){
            const float2* row = F23P + k2*11;      // wave-uniform -> s_load
            float re = x0.x, im = x0.y;
            #pragma unroll
            for (int m = 0; m < 11; ++m){
                float c = row[m].x, s = row[m].y;
                re += u[m].x*c - d[m].y*s;
                im += u[m].y*c + d[m].x*s;
            }
            X[ll*369 + k1 + 16*k2] = make_float2(re, im);
        }
    }
    __syncthreads();

    // Phase 3c: transposed store Bt[(b*368+k)*640 + h0 + l]
    const float sc = 0.052129458158616354f;        // 1/sqrt(368)
    for (int i = t; i < FROWS*368; i += 512){
        int k = i >> 2, ll = i & 3;
        float2 v = X[ll*369 + k];
        float s = (k & 1) ? -sc : sc;              // (-1)^k
        Bt[((size_t)(b*368 + k))*640 + h0 + ll] = make_float2(v.x*s, v.y*s);
    }
}

// ---------------------------------------------------------------------------
// K2 (ffthb): H-axis centered IFFT (640 = 16*8*5) fused with the B-axis
// centered FFT8 + magnitude. Block = one w, all 8 batches (8 lines x 640 in
// LDS). After the in-LDS H-FFT, the 8 batch values at each h are resident ->
// FFT8 across l + |.| immediately. Signs: all (-1)^k output signs are common
// per-pixel factors killed by |.|; only the B input sign (-1)^l and the scale
// 1/sqrt(640*8) survive. Mag stored as float [k][w][h] (h-coalesced).
// ---------------------------------------------------------------------------
__global__ __launch_bounds__(256) void ffthb_kernel(const float2* __restrict__ Bt,
                                                    const float2* __restrict__ TW640P,
                                                    const float2* __restrict__ TW40P,
                                                    float* __restrict__ Mag){
    __shared__ float2 X[8*HP];            // 41,280 B
    int t = threadIdx.x;
    int w = blockIdx.x;

    // stage: 8 b-lines of 640, coalesced; fold (-1)^n (H centering input)
    for (int i = t; i < 8*640; i += 256){
        int l = i / 640, n = i - l*640;
        float2 v = Bt[((size_t)(l*368 + w))*640 + n];
        float s = (n & 1) ? -1.f : 1.f;
        X[l*HP + n] = make_float2(v.x*s, v.y*s);
    }
    __syncthreads();

    // stage 1: FFT16 over n1, items (l,n2) = 320
    for (int it = t; it < 320; it += 256){
        int l = it & 7, n2 = it >> 3;
        float2 xr[16], Xo[16];
        #pragma unroll
        for (int n1 = 0; n1 < 16; ++n1) xr[n1] = X[l*HP + 40*n1 + n2];
        fft16p_(xr, Xo);
        const float2* row = TW640P + n2*16;
        #pragma unroll
        for (int k1 = 0; k1 < 16; ++k1)
            X[l*HP + 40*k1 + n2] = cmulv_(Xo[k1], row[k1]);
    }
    __syncthreads();

    // stage 2a: FFT8 over m1, items (l,k1,m2) = 640
    for (int it = t; it < 640; it += 256){
        int l = it & 7, k1 = (it >> 3) & 15, m2 = it >> 7;
        float2 xr[8], Xo[8];
        #pragma unroll
        for (int m1 = 0; m1 < 8; ++m1) xr[m1] = X[l*HP + 40*k1 + 5*m1 + m2];
        fft8p_(xr, Xo);
        const float2* row = TW40P + m2*8;
        #pragma unroll
        for (int j1 = 0; j1 < 8; ++j1)
            X[l*HP + 40*k1 + 5*j1 + m2] = cmulv_(Xo[j1], row[j1]);
    }
    __syncthreads();

    // stage 2b: DFT5 over m2 via pairs, 1024 units = (l,k1,j1), 4 per thread
    {
        const float CK1[5] = {1.f,  0.30901699437494745f, -0.8090169943749475f, -0.8090169943749475f,  0.30901699437494745f};
        const float SK1[5] = {0.f,  0.9510565162951535f,   0.5877852522924731f, -0.5877852522924731f, -0.9510565162951535f};
        const float CK2[5] = {1.f, -0.8090169943749475f,   0.30901699437494745f, 0.30901699437494745f, -0.8090169943749475f};
        const float SK2[5] = {0.f,  0.5877852522924731f,  -0.9510565162951535f,  0.9510565162951535f, -0.5877852522924731f};
        float2 p[4][5];
        int ui[4];
        #pragma unroll
        for (int i = 0; i < 4; ++i){
            int u = t + 256*i;
            ui[u >= 1024 ? 0 : i] = u;   // (always < 1024: 256*4 = 1024 exactly)
            ui[i] = u;
            int l = u & 7, k1 = (u >> 3) & 15, j1 = u >> 7;
            #pragma unroll
            for (int m2 = 0; m2 < 5; ++m2)
                p[i][m2] = X[l*HP + 40*k1 + 5*j1 + m2];
        }
        __syncthreads();
        #pragma unroll
        for (int i = 0; i < 4; ++i){
            int u = ui[i];
            int l = u & 7, k1 = (u >> 3) & 15, j1 = u >> 7;
            float2 ua = cadd_(p[i][1], p[i][4]), da = csub_(p[i][1], p[i][4]);
            float2 ub = cadd_(p[i][2], p[i][3]), db = csub_(p[i][2], p[i][3]);
            #pragma unroll
            for (int j2 = 0; j2 < 5; ++j2){
                float c1v = CK1[j2], s1v = SK1[j2], c2v = CK2[j2], s2v = SK2[j2];
                float re = p[i][0].x + ua.x*c1v - da.y*s1v + ub.x*c2v - db.y*s2v;
                float im = p[i][0].y + ua.y*c1v + da.x*s1v + ub.y*c2v + db.x*s2v;
                X[l*HP + k1 + 16*j1 + 128*j2] = make_float2(re, im);
            }
        }
    }
    __syncthreads();

    // B-phase: centered FFT8 across l at each h + magnitude.
    // Input sign (-1)^l, combined scale 1/sqrt(640*8); output signs die in |.|
    const float SC = 0.013975424859373685f;        // 1/sqrt(640*8)
    for (int hh = t; hh < 640; hh += 256){
        float2 x[8], Xo[8];
        #pragma unroll
        for (int l = 0; l < 8; ++l){
            float2 v = X[l*HP + hh];
            float s = (l & 1) ? -SC : SC;
            x[l] = make_float2(v.x*s, v.y*s);
        }
        fft8p_(x, Xo);
        #pragma unroll
        for (int k = 0; k < 8; ++k){
            float mag = sqrtf(Xo[k].x*Xo[k].x + Xo[k].y*Xo[k].y);
            Mag[((size_t)(k*368 + w))*640 + hh] = mag;
        }
    }
}

// ---------------------------------------------------------------------------
// K3 (tail): fp16-emulated conv2(1x1, [im,img]) + leaky + conv3x3 + leaky.
// Mag[k][w][h]: pass 1a reads h-coalesced; pass 1b reads img w-coalesced.
// ---------------------------------------------------------------------------
__global__ __launch_bounds__(256) void tail_kernel(const float* __restrict__ Mag,
                                  const float* __restrict__ img,
                                  const float* __restrict__ w2,
                                  const float* __restrict__ b2,
                                  const float* __restrict__ wi,
                                  const float* __restrict__ bi,
                                  float* __restrict__ out){
    __shared__ float Pl[8][TS+2][TS+3];            // pitch 19
    int t = threadIdx.x;
    int ty0 = (blockIdx.x / 23) * TS;              // 40 tiles over h
    int tx0 = (blockIdx.x % 23) * TS;              // 23 tiles over w

    float w2h0 = __half2float(__float2half(w2[0]));
    float w2h1 = __half2float(__float2half(w2[1]));
    float b2h  = __half2float(__float2half(b2[0]));

    // pass 1a: load |ifft| tile from Mag, lanes sweep h (coalesced runs)
    for (int idx = t; idx < (TS+2)*(TS+2); idx += 256){
        int hx = idx / (TS+2), hy = idx - hx*(TS+2);
        int hh = ty0 - 1 + hy, ww = tx0 - 1 + hx;
        int hc = min(max(hh, 0), H_-1), wc = min(max(ww, 0), W_-1);
        #pragma unroll
        for (int k = 0; k < 8; ++k){
            float mag = Mag[((size_t)(k*368 + wc))*640 + hc];
            Pl[k][hy][hx] = __half2float(__float2half(mag));
        }
    }
    __syncthreads();

    // pass 1b: conv2 with img, lanes sweep w (coalesced img reads)
    for (int idx = t; idx < (TS+2)*(TS+2); idx += 256){
        int hy = idx / (TS+2), hx = idx - hy*(TS+2);
        int hh = ty0 - 1 + hy, ww = tx0 - 1 + hx;
        bool inb = (hh >= 0) && (hh < H_) && (ww >= 0) && (ww < W_);
        int hc = min(max(hh, 0), H_-1), wc = min(max(ww, 0), W_-1);
        float inbf = inb ? 1.f : 0.f;
        #pragma unroll
        for (int k = 0; k < 8; ++k){
            float g = __half2float(__float2half(img[(size_t)k*HW_ + hc*W_ + wc]));
            float a = Pl[k][hy][hx];
            float o = leaky_(a*w2h0 + g*w2h1 + b2h);
            o = __half2float(__float2half(o));
            Pl[k][hy][hx] = o * inbf;              // zero-pad outside image
        }
    }
    __syncthreads();

    // stage 2: conv3x3 from LDS, 256 spatial px x 8 batch per block
    int sy = t >> 4, sx = t & 15;
    float wv[9];
    #pragma unroll
    for (int q = 0; q < 9; ++q) wv[q] = wi[q];
    float bi0 = bi[0];
    #pragma unroll
    for (int k = 0; k < 8; ++k){
        float acc = bi0;
        #pragma unroll
        for (int dy = 0; dy < 3; ++dy)
            #pragma unroll
            for (int dx = 0; dx < 3; ++dx)
                acc += wv[dy*3+dx] * Pl[k][sy+dy][sx+dx];
        out[((size_t)k*H_ + ty0+sy)*W_ + tx0+sx] = leaky_(acc);
    }
}

// ---------------------------------------------------------------------------
// Workspace layout (bytes):
//   Bt     : float2[NP]    @ 0            (15,073,280)   [b][w][h]
//   Mag    : float[NP]     @ 15,073,280   ( 7,536,640)   [k][w][h]
//   tables : float2[1301]  @ 30,146,560   (10,408)
// ---------------------------------------------------------------------------
extern "C" void kernel_launch(void* const* d_in, const int* in_sizes, int n_in,
                              void* d_out, int out_size, void* d_ws, size_t ws_size,
                              hipStream_t stream){
    const float* img = (const float*)d_in[0];
    const float* ksp = (const float*)d_in[1];
    const float* wk  = (const float*)d_in[2];
    const float* bk  = (const float*)d_in[3];
    const float* w1  = (const float*)d_in[4];
    const float* b1  = (const float*)d_in[5];
    const float* w2  = (const float*)d_in[6];
    const float* b2  = (const float*)d_in[7];
    const float* wi  = (const float*)d_in[8];
    const float* bi  = (const float*)d_in[9];

    char* ws = (char*)d_ws;
    float2* Bt  = (float2*)(ws + 0);
    float*  Mag = (float*)(ws + 15073280);
    float2* T   = (float2*)(ws + 30146560);
    float2* TW368P = T + 0;
    float2* TW640P = T + 368;
    float2* TW40P  = T + 1008;
    float2* F23P   = T + 1048;
    float* out  = (float*)d_out;

    init_tables_kernel<<<6, 256, 0, stream>>>(T);

    kfftw_kernel<<<B_*(H_/FROWS), 512, 0, stream>>>(ksp, wk, bk, w1, b1,
                                                    TW368P, F23P, Bt);
    ffthb_kernel<<<W_, 256, 0, stream>>>(Bt, TW640P, TW40P, Mag);
    tail_kernel<<<(H_/TS)*(W_/TS), 256, 0, stream>>>(Mag, img, w2, b2, wi, bi, out);
}

// Round 13
// 172.550 us; speedup vs baseline: 1.1067x; 1.1067x over previous
//
#include <hip/hip_runtime.h>
#include <hip/hip_fp16.h>
#include <math.h>

// Problem dims
#define B_ 8
#define H_ 640
#define W_ 368
#define HW_ (H_*W_)
#define NP_ (B_*H_*W_)   // 1,884,160

#define FROWS 4          // h-rows per block in fused kbranch+fftW kernel
#define HP 645           // LDS pitch (float2) for ffthb kernel
#define TS 16            // spatial tile for fused tail kernel

typedef __attribute__((ext_vector_type(8))) short v8s;   // 8 bf16 (4 VGPR)
typedef __attribute__((ext_vector_type(4))) float v4f;   // MFMA acc

__device__ __forceinline__ float leaky_(float x){ return fmaxf(x, 0.01f*x); }

// fp32 -> bf16 round-to-nearest-even
__device__ __forceinline__ unsigned short f2bf(float x){
    unsigned u = __float_as_uint(x);
    u += 0x7FFFu + ((u >> 16) & 1u);
    return (unsigned short)(u >> 16);
}

__device__ __forceinline__ float2 cadd_(float2 a, float2 b){ return make_float2(a.x+b.x, a.y+b.y); }
__device__ __forceinline__ float2 csub_(float2 a, float2 b){ return make_float2(a.x-b.x, a.y-b.y); }
__device__ __forceinline__ float2 cmul_(float2 a, float c, float s){
    return make_float2(a.x*c - a.y*s, a.x*s + a.y*c);
}
__device__ __forceinline__ float2 cmulv_(float2 a, float2 w){
    return make_float2(a.x*w.x - a.y*w.y, a.x*w.y + a.y*w.x);
}

// DFT4 with +i convention
__device__ __forceinline__ void dft4p_(float2 p0, float2 p1, float2 p2, float2 p3,
                                       float2& z0, float2& z1, float2& z2, float2& z3){
    float2 s0 = cadd_(p0,p2), d0 = csub_(p0,p2);
    float2 s1 = cadd_(p1,p3), d1 = csub_(p1,p3);
    z0 = cadd_(s0,s1);
    z2 = csub_(s0,s1);
    z1 = make_float2(d0.x - d1.y, d0.y + d1.x);
    z3 = make_float2(d0.x + d1.y, d0.y - d1.x);
}

// 16-point DFT, +i convention
__device__ __forceinline__ void fft16p_(const float2* x, float2* X){
    const float C1 = 0.9238795325112867f, S1 = 0.3826834323650898f;
    const float R  = 0.7071067811865476f;
    float2 Y[4][4];
    #pragma unroll
    for (int b = 0; b < 4; ++b)
        dft4p_(x[b], x[4+b], x[8+b], x[12+b], Y[b][0], Y[b][1], Y[b][2], Y[b][3]);
    Y[1][1] = cmul_(Y[1][1],  C1,  S1);
    Y[1][2] = cmul_(Y[1][2],   R,   R);
    Y[1][3] = cmul_(Y[1][3],  S1,  C1);
    Y[2][1] = cmul_(Y[2][1],   R,   R);
    Y[2][2] = make_float2(-Y[2][2].y, Y[2][2].x);
    Y[2][3] = cmul_(Y[2][3],  -R,   R);
    Y[3][1] = cmul_(Y[3][1],  S1,  C1);
    Y[3][2] = cmul_(Y[3][2],  -R,   R);
    Y[3][3] = cmul_(Y[3][3], -C1, -S1);
    #pragma unroll
    for (int c = 0; c < 4; ++c)
        dft4p_(Y[0][c], Y[1][c], Y[2][c], Y[3][c], X[c], X[c+4], X[c+8], X[c+12]);
}

// 8-point DFT, +i convention
__device__ __forceinline__ void fft8p_(const float2* x, float2* X){
    const float R = 0.7071067811865476f;
    float2 Y0[4], Y1[4];
    dft4p_(x[0], x[2], x[4], x[6], Y0[0], Y0[1], Y0[2], Y0[3]);
    dft4p_(x[1], x[3], x[5], x[7], Y1[0], Y1[1], Y1[2], Y1[3]);
    float2 T0 = Y1[0];
    float2 T1 = cmul_(Y1[1],  R, R);
    float2 T2 = make_float2(-Y1[2].y, Y1[2].x);
    float2 T3 = cmul_(Y1[3], -R, R);
    X[0] = cadd_(Y0[0], T0);  X[4] = csub_(Y0[0], T0);
    X[1] = cadd_(Y0[1], T1);  X[5] = csub_(Y0[1], T1);
    X[2] = cadd_(Y0[2], T2);  X[6] = csub_(Y0[2], T2);
    X[3] = cadd_(Y0[3], T3);  X[7] = csub_(Y0[3], T3);
}

// ---------------------------------------------------------------------------
// Tables (float2 indices in T):
//   TW368P @    0 (368)  [n2*16+k1] = e^{+2pi i k1 n2/368}
//   TW640P @  368 (640)  [n2*16+k1] = e^{+2pi i k1 n2/640}
//   TW40P  @ 1008 ( 40)  [m2*8+j1]  = e^{+2pi i j1 m2/40}
//   F23P   @ 1048 (253)  [k2*11+m-1]= (cos,sin)(2pi k2 m/23)
// ---------------------------------------------------------------------------
__global__ void init_tables_kernel(float2* __restrict__ T){
    int i = blockIdx.x*blockDim.x + threadIdx.x;
    if (i >= 1301) return;
    int r, c, modN; int j;
    if      (i <  368){ j = i;        r = j%16; c = j/16; modN = 368; }
    else if (i < 1008){ j = i-368;    r = j%16; c = j/16; modN = 640; }
    else if (i < 1048){ j = i-1008;   r = j%8;  c = j/8;  modN = 40;  }
    else              { j = i-1048;   r = j/11; c = j%11 + 1; modN = 23; }
    int t = (int)(((long long)r * c) % modN);
    if (t > modN/2) t -= modN;
    float ang = (float)(6.283185307179586 * ((double)t / (double)modN));
    float s, co;
    sincosf(ang, &s, &co);
    T[i] = make_float2(co, s);
}

// ---------------------------------------------------------------------------
// K1 (fused kbranch + W-FFT), 256 threads (round-11 revert; the 512-thread
// variant regressed 68->88 us at 21% occupancy). Block = 4 h rows of one b.
// ---------------------------------------------------------------------------
__global__ __launch_bounds__(256) void kfftw_kernel(const float* __restrict__ ksp,
                               const float* __restrict__ wk,
                               const float* __restrict__ bk,
                               const float* __restrict__ w1,
                               const float* __restrict__ b1,
                               const float2* __restrict__ TW368P,
                               const float2* __restrict__ F23P,
                               float2* __restrict__ Bt){
    __shared__ unsigned short Sb[4836];     // 6 rows x 2ch x 372 + zero region
    __shared__ unsigned short Wr[4*512];    // per-wave 16px x 32oc transpose buf
    __shared__ float2 X[FROWS*369];         // fft working set (11,808 B)
    int t = threadIdx.x;
    int blk = blockIdx.x;                   // b*160 + h0/4
    int b  = blk / 160;
    int h0 = (blk - b*160) * FROWS;

    // Phase 1: stage rows h0-1 .. h0+4, both channels, halo col +1
    for (int seg = 0; seg < 12; ++seg){
        int r = seg >> 1, ic = seg & 1;
        int hh = h0 - 1 + r;
        int ok = ((unsigned)hh < 640u);
        const float* base = ksp + ((size_t)(b*2 + ic)*640 + (ok ? hh : 0))*368;
        for (int col = t; col < 372; col += 256){
            int c = col - 1;
            float v = (ok && (unsigned)c < 368u) ? base[c] : 0.f;
            Sb[seg*372 + col] = f2bf(v);
        }
    }
    for (int i = t; i < 372; i += 256) Sb[4464 + i] = 0;   // zero pad for k>=18

    int lane = t & 63, wave = t >> 6;
    int oc = lane & 15, q = lane >> 4;
    int l = wave;                           // wave owns row h0+l

    int off[8];
    v8s bf0, bf1, b2f;
    #pragma unroll
    for (int j = 0; j < 8; ++j){
        int kk = q*8 + j;
        if (kk < 18){
            int ic = (kk >= 9) ? 1 : 0;
            int tt = kk - ic*9;
            int ty = tt/3, tx = tt - ty*3;
            off[j] = ((ty + l)*2 + ic)*372 + tx;
            bf0[j] = (short)f2bf(wk[oc*18 + kk]);
            bf1[j] = (short)f2bf(wk[(oc+16)*18 + kk]);
        } else {
            off[j] = 4464;                  // zeroed region
            bf0[j] = 0; bf1[j] = 0;
        }
        b2f[j] = (oc < 2) ? (short)f2bf(w1[oc*32 + kk]) : (short)0;
    }
    float bk0 = bk[oc], bk1 = bk[oc+16];
    float biasn = (oc == 1) ? b1[1] : b1[0];
    unsigned short* Wrw = Wr + (wave << 9);
    __syncthreads();

    // Phase 2: 23 groups of 16 px per wave (row l)
    for (int g = 0; g < 23; ++g){
        int w0m = g*16 + oc;
        v8s af;
        #pragma unroll
        for (int j = 0; j < 8; ++j) af[j] = (short)Sb[off[j] + w0m];
        v4f d0 = {0.f,0.f,0.f,0.f}, d1 = {0.f,0.f,0.f,0.f};
        d0 = __builtin_amdgcn_mfma_f32_16x16x32_bf16(af, bf0, d0, 0, 0, 0);
        d1 = __builtin_amdgcn_mfma_f32_16x16x32_bf16(af, bf1, d1, 0, 0, 0);
        #pragma unroll
        for (int r = 0; r < 4; ++r){
            int px = q*4 + r;
            Wrw[px*32 + oc]      = f2bf(leaky_(d0[r] + bk0));
            Wrw[px*32 + 16 + oc] = f2bf(leaky_(d1[r] + bk1));
        }
        asm volatile("s_waitcnt lgkmcnt(0)" ::: "memory");
        const v8s* ap = (const v8s*)(Wrw + oc*32);
        v8s a2 = ap[q];
        v4f d2 = {0.f,0.f,0.f,0.f};
        d2 = __builtin_amdgcn_mfma_f32_16x16x32_bf16(a2, b2f, d2, 0, 0, 0);
        float vals[4], ov[4];
        #pragma unroll
        for (int r = 0; r < 4; ++r){
            vals[r] = leaky_(biasn + d2[r]);
            ov[r] = __shfl_xor(vals[r], 1);          // o1 (col 1) -> col-0 lane
        }
        if (oc == 0){
            int px = g*16 + q*4;                     // even -> signs +,-,+,-
            X[l*369 + px  ] = make_float2( vals[0],  ov[0]);
            X[l*369 + px+1] = make_float2(-vals[1], -ov[1]);
            X[l*369 + px+2] = make_float2( vals[2],  ov[2]);
            X[l*369 + px+3] = make_float2(-vals[3], -ov[3]);
        }
        asm volatile("s_waitcnt lgkmcnt(0)" ::: "memory");  // Wr reuse fence
    }
    __syncthreads();

    // Phase 3a: FFT16 over n1, items (l,n2) = 92
    if (t < 92){
        int ll = t & 3, n2 = t >> 2;
        float2 xr[16], Xo[16];
        #pragma unroll
        for (int n1 = 0; n1 < 16; ++n1) xr[n1] = X[ll*369 + 23*n1 + n2];
        fft16p_(xr, Xo);
        const float2* row = TW368P + n2*16;
        #pragma unroll
        for (int k1 = 0; k1 < 16; ++k1)
            X[ll*369 + 23*k1 + n2] = cmulv_(Xo[k1], row[k1]);
    }
    __syncthreads();

    // Phase 3b: DFT23 via pairs; 256 units = (l,k1,quarter)
    {
        int ll = t & 3, k1 = (t >> 2) & 15, qr = t >> 6;   // qr wave-uniform
        const float2* xp = X + ll*369 + 23*k1;
        float2 x0 = xp[0];
        float2 u[11], d[11];
        #pragma unroll
        for (int m = 1; m <= 11; ++m){
            float2 a = xp[m], bb = xp[23-m];
            u[m-1] = cadd_(a, bb);
            d[m-1] = csub_(a, bb);
        }
        __syncthreads();
        int k2beg = qr*6;
        int k2end = (qr == 3) ? 23 : k2beg + 6;
        for (int k2 = k2beg; k2 < k2end; ++k2){
            const float2* row = F23P + k2*11;      // wave-uniform -> s_load
            float re = x0.x, im = x0.y;
            #pragma unroll
            for (int m = 0; m < 11; ++m){
                float c = row[m].x, s = row[m].y;
                re += u[m].x*c - d[m].y*s;
                im += u[m].y*c + d[m].x*s;
            }
            X[ll*369 + k1 + 16*k2] = make_float2(re, im);
        }
    }
    __syncthreads();

    // Phase 3c: transposed store Bt[(b*368+k)*640 + h0 + l]
    const float sc = 0.052129458158616354f;        // 1/sqrt(368)
    for (int i = t; i < FROWS*368; i += 256){
        int k = i >> 2, ll = i & 3;
        float2 v = X[ll*369 + k];
        float s = (k & 1) ? -sc : sc;              // (-1)^k
        Bt[((size_t)(b*368 + k))*640 + h0 + ll] = make_float2(v.x*s, v.y*s);
    }
}

// ---------------------------------------------------------------------------
// K2 (ffthb v2, wave-ownership): H-axis centered IFFT (640 = 16*8*5) + B-axis
// centered FFT8 + |.|. 512 threads, block = one w; WAVE l OWNS LINE l — all
// H-FFT stages for a line run inside one wave with NO block barriers (DS ops
// from one wave are serviced in order; per-wave lgkmcnt waits only). Single
// __syncthreads before the cross-line B-phase. Output signs die under |.|;
// only input signs (-1)^n, (-1)^l and scale 1/sqrt(640*8) survive.
// ---------------------------------------------------------------------------
__global__ __launch_bounds__(512) void ffthb_kernel(const float2* __restrict__ Bt,
                                                    const float2* __restrict__ TW640P,
                                                    const float2* __restrict__ TW40P,
                                                    float* __restrict__ Mag){
    __shared__ float2 X[8*HP];            // 41,280 B
    int t = threadIdx.x;
    int lane = t & 63, l = t >> 6;        // wave index = batch line
    int w = blockIdx.x;
    float2* Xl = X + l*HP;

    // staging: own line, coalesced 512B/wave; fold (-1)^n
    const float2* src = Bt + ((size_t)(l*368 + w))*640;
    for (int n = lane; n < 640; n += 64){
        float2 v = src[n];
        float s = (n & 1) ? -1.f : 1.f;
        Xl[n] = make_float2(v.x*s, v.y*s);
    }
    asm volatile("s_waitcnt vmcnt(0) lgkmcnt(0)" ::: "memory");

    // stage 1: FFT16 over n1; 40 items (n2), lanes 0..39
    if (lane < 40){
        int n2 = lane;
        float2 xr[16], Xo[16];
        #pragma unroll
        for (int n1 = 0; n1 < 16; ++n1) xr[n1] = Xl[40*n1 + n2];
        fft16p_(xr, Xo);
        const float2* row = TW640P + n2*16;
        #pragma unroll
        for (int k1 = 0; k1 < 16; ++k1)
            Xl[40*k1 + n2] = cmulv_(Xo[k1], row[k1]);
    }
    asm volatile("s_waitcnt lgkmcnt(0)" ::: "memory");

    // stage 2a: FFT8 over m1; 80 items (k1,m2) over 64 lanes
    for (int it = lane; it < 80; it += 64){
        int k1 = it & 15, m2 = it >> 4;
        float2 xr[8], Xo[8];
        #pragma unroll
        for (int m1 = 0; m1 < 8; ++m1) xr[m1] = Xl[40*k1 + 5*m1 + m2];
        fft8p_(xr, Xo);
        const float2* row = TW40P + m2*8;
        #pragma unroll
        for (int j1 = 0; j1 < 8; ++j1)
            Xl[40*k1 + 5*j1 + m2] = cmulv_(Xo[j1], row[j1]);
    }
    asm volatile("s_waitcnt lgkmcnt(0)" ::: "memory");

    // stage 2b: DFT5 over m2 via pairs; 128 items (k1,j1), 2 per lane.
    // All reads issue before any write (DS per-wave in-order -> safe).
    {
        const float CK1[5] = {1.f,  0.30901699437494745f, -0.8090169943749475f, -0.8090169943749475f,  0.30901699437494745f};
        const float SK1[5] = {0.f,  0.9510565162951535f,   0.5877852522924731f, -0.5877852522924731f, -0.9510565162951535f};
        const float CK2[5] = {1.f, -0.8090169943749475f,   0.30901699437494745f, 0.30901699437494745f, -0.8090169943749475f};
        const float SK2[5] = {0.f,  0.5877852522924731f,  -0.9510565162951535f,  0.9510565162951535f, -0.5877852522924731f};
        int itA = lane, itB = lane + 64;
        int kA = itA & 15, jA = itA >> 4;
        int kB = itB & 15, jB = itB >> 4;
        float2 pA[5], pB[5];
        #pragma unroll
        for (int m2 = 0; m2 < 5; ++m2) pA[m2] = Xl[40*kA + 5*jA + m2];
        #pragma unroll
        for (int m2 = 0; m2 < 5; ++m2) pB[m2] = Xl[40*kB + 5*jB + m2];
        asm volatile("s_waitcnt lgkmcnt(0)" ::: "memory");
        float2 uAa = cadd_(pA[1], pA[4]), dAa = csub_(pA[1], pA[4]);
        float2 uAb = cadd_(pA[2], pA[3]), dAb = csub_(pA[2], pA[3]);
        float2 uBa = cadd_(pB[1], pB[4]), dBa = csub_(pB[1], pB[4]);
        float2 uBb = cadd_(pB[2], pB[3]), dBb = csub_(pB[2], pB[3]);
        #pragma unroll
        for (int j2 = 0; j2 < 5; ++j2){
            float c1v = CK1[j2], s1v = SK1[j2], c2v = CK2[j2], s2v = SK2[j2];
            float reA = pA[0].x + uAa.x*c1v - dAa.y*s1v + uAb.x*c2v - dAb.y*s2v;
            float imA = pA[0].y + uAa.y*c1v + dAa.x*s1v + uAb.y*c2v + dAb.x*s2v;
            float reB = pB[0].x + uBa.x*c1v - dBa.y*s1v + uBb.x*c2v - dBb.y*s2v;
            float imB = pB[0].y + uBa.y*c1v + dBa.x*s1v + uBb.y*c2v + dBb.x*s2v;
            Xl[kA + 16*jA + 128*j2] = make_float2(reA, imA);
            Xl[kB + 16*jB + 128*j2] = make_float2(reB, imB);
        }
    }
    __syncthreads();   // only barrier: B-phase reads all 8 lines

    // B-phase: centered FFT8 across l at each h + magnitude.
    const float SC = 0.013975424859373685f;        // 1/sqrt(640*8)
    for (int hh = t; hh < 640; hh += 512){
        float2 x[8], Xo[8];
        #pragma unroll
        for (int ll = 0; ll < 8; ++ll){
            float2 v = X[ll*HP + hh];
            float s = (ll & 1) ? -SC : SC;
            x[ll] = make_float2(v.x*s, v.y*s);
        }
        fft8p_(x, Xo);
        #pragma unroll
        for (int k = 0; k < 8; ++k){
            float mag = sqrtf(Xo[k].x*Xo[k].x + Xo[k].y*Xo[k].y);
            Mag[((size_t)(k*368 + w))*640 + hh] = mag;
        }
    }
}

// ---------------------------------------------------------------------------
// K3 (tail): fp16-emulated conv2(1x1, [im,img]) + leaky + conv3x3 + leaky.
// Mag[k][w][h]: pass 1a reads h-coalesced; pass 1b reads img w-coalesced.
// ---------------------------------------------------------------------------
__global__ __launch_bounds__(256) void tail_kernel(const float* __restrict__ Mag,
                                  const float* __restrict__ img,
                                  const float* __restrict__ w2,
                                  const float* __restrict__ b2,
                                  const float* __restrict__ wi,
                                  const float* __restrict__ bi,
                                  float* __restrict__ out){
    __shared__ float Pl[8][TS+2][TS+3];            // pitch 19
    int t = threadIdx.x;
    int ty0 = (blockIdx.x / 23) * TS;              // 40 tiles over h
    int tx0 = (blockIdx.x % 23) * TS;              // 23 tiles over w

    float w2h0 = __half2float(__float2half(w2[0]));
    float w2h1 = __half2float(__float2half(w2[1]));
    float b2h  = __half2float(__float2half(b2[0]));

    // pass 1a: load |ifft| tile from Mag, lanes sweep h (coalesced runs)
    for (int idx = t; idx < (TS+2)*(TS+2); idx += 256){
        int hx = idx / (TS+2), hy = idx - hx*(TS+2);
        int hh = ty0 - 1 + hy, ww = tx0 - 1 + hx;
        int hc = min(max(hh, 0), H_-1), wc = min(max(ww, 0), W_-1);
        #pragma unroll
        for (int k = 0; k < 8; ++k){
            float mag = Mag[((size_t)(k*368 + wc))*640 + hc];
            Pl[k][hy][hx] = __half2float(__float2half(mag));
        }
    }
    __syncthreads();

    // pass 1b: conv2 with img, lanes sweep w (coalesced img reads)
    for (int idx = t; idx < (TS+2)*(TS+2); idx += 256){
        int hy = idx / (TS+2), hx = idx - hy*(TS+2);
        int hh = ty0 - 1 + hy, ww = tx0 - 1 + hx;
        bool inb = (hh >= 0) && (hh < H_) && (ww >= 0) && (ww < W_);
        int hc = min(max(hh, 0), H_-1), wc = min(max(ww, 0), W_-1);
        float inbf = inb ? 1.f : 0.f;
        #pragma unroll
        for (int k = 0; k < 8; ++k){
            float g = __half2float(__float2half(img[(size_t)k*HW_ + hc*W_ + wc]));
            float a = Pl[k][hy][hx];
            float o = leaky_(a*w2h0 + g*w2h1 + b2h);
            o = __half2float(__float2half(o));
            Pl[k][hy][hx] = o * inbf;              // zero-pad outside image
        }
    }
    __syncthreads();

    // stage 2: conv3x3 from LDS, 256 spatial px x 8 batch per block
    int sy = t >> 4, sx = t & 15;
    float wv[9];
    #pragma unroll
    for (int q = 0; q < 9; ++q) wv[q] = wi[q];
    float bi0 = bi[0];
    #pragma unroll
    for (int k = 0; k < 8; ++k){
        float acc = bi0;
        #pragma unroll
        for (int dy = 0; dy < 3; ++dy)
            #pragma unroll
            for (int dx = 0; dx < 3; ++dx)
                acc += wv[dy*3+dx] * Pl[k][sy+dy][sx+dx];
        out[((size_t)k*H_ + ty0+sy)*W_ + tx0+sx] = leaky_(acc);
    }
}

// ---------------------------------------------------------------------------
// Workspace layout (bytes):
//   Bt     : float2[NP]    @ 0            (15,073,280)   [b][w][h]
//   Mag    : float[NP]     @ 15,073,280   ( 7,536,640)   [k][w][h]
//   tables : float2[1301]  @ 30,146,560   (10,408)
// ---------------------------------------------------------------------------
extern "C" void kernel_launch(void* const* d_in, const int* in_sizes, int n_in,
                              void* d_out, int out_size, void* d_ws, size_t ws_size,
                              hipStream_t stream){
    const float* img = (const float*)d_in[0];
    const float* ksp = (const float*)d_in[1];
    const float* wk  = (const float*)d_in[2];
    const float* bk  = (const float*)d_in[3];
    const float* w1  = (const float*)d_in[4];
    const float* b1  = (const float*)d_in[5];
    const float* w2  = (const float*)d_in[6];
    const float* b2  = (const float*)d_in[7];
    const float* wi  = (const float*)d_in[8];
    const float* bi  = (const float*)d_in[9];

    char* ws = (char*)d_ws;
    float2* Bt  = (float2*)(ws + 0);
    float*  Mag = (float*)(ws + 15073280);
    float2* T   = (float2*)(ws + 30146560);
    float2* TW368P = T + 0;
    float2* TW640P = T + 368;
    float2* TW40P  = T + 1008;
    float2* F23P   = T + 1048;
    float* out  = (float*)d_out;

    init_tables_kernel<<<6, 256, 0, stream>>>(T);

    kfftw_kernel<<<B_*(H_/FROWS), 256, 0, stream>>>(ksp, wk, bk, w1, b1,
                                                    TW368P, F23P, Bt);
    ffthb_kernel<<<W_, 512, 0, stream>>>(Bt, TW640P, TW40P, Mag);
    tail_kernel<<<(H_/TS)*(W_/TS), 256, 0, stream>>>(Mag, img, w2, b2, wi, bi, out);
}